// Round 2
// baseline (271.053 us; speedup 1.0000x reference)
//
#include <hip/hip_runtime.h>
#include <hip/hip_bf16.h>

#define B_CNT 32
#define N_CNT 32
#define A_CNT 8400
#define NC_CNT 80
#define TOPK 13

// ---------------- Kernel A: align_metric / overlaps / valid per (b,n,a) ----------------
__global__ void kA(const float* __restrict__ ps, const float* __restrict__ pb,
                   const float* __restrict__ ap, const int* __restrict__ gl,
                   const float* __restrict__ gb, const float* __restrict__ mgt,
                   float* __restrict__ align, float* __restrict__ ovl,
                   unsigned char* __restrict__ valid) {
    int bn = blockIdx.x;               // 0..1023
    int b = bn >> 5;
    float4 g = ((const float4*)gb)[bn];
    bool mg = mgt[bn] > 0.f;
    int lbl = min(max(gl[bn], 0), NC_CNT - 1);
    float area_g = (g.z - g.x) * (g.w - g.y);
    const float*  psb = ps + (size_t)b * A_CNT * NC_CNT;
    const float4* pbb = (const float4*)(pb + (size_t)b * A_CNT * 4);
    size_t row = (size_t)bn * A_CNT;
    for (int a = threadIdx.x; a < A_CNT; a += 256) {
        float ax = ap[2 * a], ay = ap[2 * a + 1];
        float dmin = fminf(fminf(ax - g.x, ay - g.y), fminf(g.z - ax, g.w - ay));
        bool v = mg && (dmin > 1e-9f);
        float al = 0.f, ov = 0.f;
        if (v) {
            float4 p = pbb[a];
            float ix = fminf(g.z, p.z) - fmaxf(g.x, p.x);
            float iy = fminf(g.w, p.w) - fmaxf(g.y, p.y);
            float inter = fmaxf(ix, 0.f) * fmaxf(iy, 0.f);
            float area_p = (p.z - p.x) * (p.w - p.y);
            ov = inter / (area_g + area_p - inter + 1e-7f);
            ov = fmaxf(ov, 0.f);
            float sc = psb[(size_t)a * NC_CNT + lbl];
            float ov2 = ov * ov;
            float ov6 = ov2 * ov2 * ov2;
            al = sc * ov6;
        }
        align[row + a] = al;
        ovl[row + a] = ov;
        valid[row + a] = v ? 1 : 0;
    }
}

// ---------------- Kernel B: top-13 per (b,n) row, stable lowest-index ties ----------------
__global__ void kB(const float* __restrict__ align, const unsigned char* __restrict__ valid,
                   unsigned char* __restrict__ mask) {
    __shared__ float vals[A_CNT];
    __shared__ float rv[256];
    __shared__ int   ri[256];
    __shared__ int   sel[TOPK];
    int bn = blockIdx.x;
    size_t row = (size_t)bn * A_CNT;
    for (int a = threadIdx.x; a < A_CNT; a += 256) vals[a] = align[row + a];
    __syncthreads();
    for (int k = 0; k < TOPK; k++) {
        float best = -1.f; int bi = 0x7fffffff;
        for (int a = threadIdx.x; a < A_CNT; a += 256) {
            float v = vals[a];
            if (v > best) { best = v; bi = a; }   // ascending scan => first max kept
        }
        rv[threadIdx.x] = best; ri[threadIdx.x] = bi;
        __syncthreads();
        for (int s = 128; s > 0; s >>= 1) {
            if (threadIdx.x < s) {
                float v2 = rv[threadIdx.x + s]; int i2 = ri[threadIdx.x + s];
                if (v2 > rv[threadIdx.x] || (v2 == rv[threadIdx.x] && i2 < ri[threadIdx.x])) {
                    rv[threadIdx.x] = v2; ri[threadIdx.x] = i2;
                }
            }
            __syncthreads();
        }
        if (threadIdx.x == 0) { sel[k] = ri[0]; vals[ri[0]] = -1.f; }
        __syncthreads();
    }
    for (int a = threadIdx.x; a < A_CNT; a += 256) {
        bool s = false;
#pragma unroll
        for (int k = 0; k < TOPK; k++) s |= (sel[k] == a);
        mask[row + a] = (s && valid[row + a]) ? 1 : 0;
    }
}

// ---------------- Kernel C: fg, multi-assignment resolve, tgi, fg output ----------------
__global__ void kC(const float* __restrict__ ovl, unsigned char* __restrict__ mask,
                   int* __restrict__ tgi, float* __restrict__ out_fg) {
    int idx = blockIdx.x * 256 + threadIdx.x;
    if (idx >= B_CNT * A_CNT) return;
    int b = idx / A_CNT, a = idx - b * A_CNT;
    size_t base = (size_t)b * N_CNT * A_CNT + a;
    int fg = 0, first = -1;
    for (int n = 0; n < N_CNT; n++) {
        unsigned char m = mask[base + (size_t)n * A_CNT];
        fg += m;
        if (m && first < 0) first = n;
    }
    int t;
    if (fg > 1) {
        float bo = -1.f; int bn_ = 0;
        for (int n = 0; n < N_CNT; n++) {
            float o = ovl[base + (size_t)n * A_CNT];
            if (o > bo) { bo = o; bn_ = n; }      // first max (numpy argmax)
        }
        t = bn_;
        for (int n = 0; n < N_CNT; n++) mask[base + (size_t)n * A_CNT] = (n == t) ? 1 : 0;
        fg = 1;
    } else {
        t = (first >= 0) ? first : 0;
    }
    tgi[idx] = t;
    out_fg[idx] = (fg > 0) ? 1.f : 0.f;
}

// ---------------- Kernel D: per-(b,n) pos_align / pos_ov row maxima ----------------
__global__ void kD(const float* __restrict__ align, const float* __restrict__ ovl,
                   const unsigned char* __restrict__ mask,
                   float* __restrict__ pos_align, float* __restrict__ pos_ov) {
    __shared__ float ra[256], ro[256];
    int bn = blockIdx.x;
    size_t row = (size_t)bn * A_CNT;
    float ma = 0.f, mo = 0.f;
    for (int a = threadIdx.x; a < A_CNT; a += 256) {
        if (mask[row + a]) {
            ma = fmaxf(ma, align[row + a]);
            mo = fmaxf(mo, ovl[row + a]);
        }
    }
    ra[threadIdx.x] = ma; ro[threadIdx.x] = mo;
    __syncthreads();
    for (int s = 128; s > 0; s >>= 1) {
        if (threadIdx.x < s) {
            ra[threadIdx.x] = fmaxf(ra[threadIdx.x], ra[threadIdx.x + s]);
            ro[threadIdx.x] = fmaxf(ro[threadIdx.x], ro[threadIdx.x + s]);
        }
        __syncthreads();
    }
    if (threadIdx.x == 0) { pos_align[bn] = ra[0]; pos_ov[bn] = ro[0]; }
}

// ---------------- Kernel E: norm, target label, target bboxes ----------------
__global__ void kE(const float* __restrict__ align, const int* __restrict__ gl,
                   const float* __restrict__ gb, const int* __restrict__ tgi,
                   const float* __restrict__ out_fg, const float* __restrict__ pos_align,
                   const float* __restrict__ pos_ov, float* __restrict__ norm,
                   int* __restrict__ tlab, float* __restrict__ out_bbox) {
    int idx = blockIdx.x * 256 + threadIdx.x;
    if (idx >= B_CNT * A_CNT) return;
    int b = idx / A_CNT, a = idx - b * A_CNT;
    int t = tgi[idx];
    int bn = b * N_CNT + t;
    float nv = 0.f;
    if (out_fg[idx] > 0.f) {
        nv = align[(size_t)bn * A_CNT + a] * pos_ov[bn] / (pos_align[bn] + 1e-9f);
    }
    norm[idx] = nv;
    tlab[idx] = min(max(gl[bn], 0), NC_CNT - 1);
    ((float4*)out_bbox)[idx] = ((const float4*)gb)[bn];
}

// ---------------- Kernel F: target_scores one-hot * norm (86 MB write) ----------------
__global__ void kF(const int* __restrict__ tlab, const float* __restrict__ norm,
                   const float* __restrict__ out_fg, float* __restrict__ out_scores) {
    int idx = blockIdx.x * 256 + threadIdx.x;
    if (idx >= B_CNT * A_CNT * NC_CNT) return;
    int ba = idx / NC_CNT;
    int c = idx - ba * NC_CNT;
    float v = 0.f;
    if (out_fg[ba] > 0.f && tlab[ba] == c) v = norm[ba];
    out_scores[idx] = v;
}

extern "C" void kernel_launch(void* const* d_in, const int* in_sizes, int n_in,
                              void* d_out, int out_size, void* d_ws, size_t ws_size,
                              hipStream_t stream) {
    const float* pred_scores   = (const float*)d_in[0];   // (32, 8400, 80)
    const float* pred_bboxes   = (const float*)d_in[1];   // (32, 8400, 4)
    const float* anchor_points = (const float*)d_in[2];   // (8400, 2)
    const int*   gt_labels     = (const int*)d_in[3];     // (32, 32, 1)
    const float* gt_bboxes     = (const float*)d_in[4];   // (32, 32, 4)
    const float* mask_gt       = (const float*)d_in[5];   // (32, 32, 1)

    const int BNA = B_CNT * N_CNT * A_CNT;   // 8,601,600
    const int BA  = B_CNT * A_CNT;           // 268,800

    // workspace layout
    char* w = (char*)d_ws;
    float* align          = (float*)w;                    w += (size_t)BNA * 4;
    float* ovl            = (float*)w;                    w += (size_t)BNA * 4;
    unsigned char* valid  = (unsigned char*)w;            w += (size_t)BNA;
    unsigned char* mask   = (unsigned char*)w;            w += (size_t)BNA;
    int*   tgi            = (int*)w;                      w += (size_t)BA * 4;
    float* pos_align      = (float*)w;                    w += (size_t)B_CNT * N_CNT * 4;
    float* pos_ov         = (float*)w;                    w += (size_t)B_CNT * N_CNT * 4;
    float* norm           = (float*)w;                    w += (size_t)BA * 4;
    int*   tlab           = (int*)w;                      w += (size_t)BA * 4;

    // output layout: bboxes (BA*4) | scores (BA*80) | fg (BA)
    float* out_bbox   = (float*)d_out;
    float* out_scores = out_bbox + (size_t)BA * 4;
    float* out_fg     = out_scores + (size_t)BA * NC_CNT;

    dim3 blk(256);
    kA<<<dim3(B_CNT * N_CNT), blk, 0, stream>>>(pred_scores, pred_bboxes, anchor_points,
                                                gt_labels, gt_bboxes, mask_gt,
                                                align, ovl, valid);
    kB<<<dim3(B_CNT * N_CNT), blk, 0, stream>>>(align, valid, mask);
    kC<<<dim3((BA + 255) / 256), blk, 0, stream>>>(ovl, mask, tgi, out_fg);
    kD<<<dim3(B_CNT * N_CNT), blk, 0, stream>>>(align, ovl, mask, pos_align, pos_ov);
    kE<<<dim3((BA + 255) / 256), blk, 0, stream>>>(align, gt_labels, gt_bboxes, tgi, out_fg,
                                                   pos_align, pos_ov, norm, tlab, out_bbox);
    kF<<<dim3((BA * NC_CNT + 255) / 256), blk, 0, stream>>>(tlab, norm, out_fg, out_scores);
}

// Round 3
// 269.113 us; speedup vs baseline: 1.0072x; 1.0072x over previous
//
#include <hip/hip_runtime.h>

#define B_CNT 32
#define N_CNT 32
#define A_CNT 8400
#define NC_CNT 80
#define TOPK 13
#define EPS_IN 1e-9f

// ---------- K1: per (b,n) row: compute align in LDS, top-13, compact lists + posmask bits ----------
__global__ void __launch_bounds__(256) k1(const float* __restrict__ ps, const float* __restrict__ pb,
        const float* __restrict__ ap, const int* __restrict__ gl,
        const float* __restrict__ gb, const float* __restrict__ mgt,
        unsigned int* __restrict__ posmask, int* __restrict__ cIdx,
        float* __restrict__ cAl, float* __restrict__ cOv) {
    __shared__ float vals[A_CNT];
    __shared__ unsigned char validb[A_CNT];
    __shared__ float rv[256];
    __shared__ int   ri[256];
    __shared__ int   sel[TOPK];
    __shared__ float selAl[TOPK];
    int bn = blockIdx.x;            // b*32+n
    int b = bn >> 5, n = bn & 31;
    float4 g = ((const float4*)gb)[bn];
    bool mg = mgt[bn] > 0.f;
    int lbl = min(max(gl[bn], 0), NC_CNT - 1);
    float area_g = (g.z - g.x) * (g.w - g.y);
    const float*  psb = ps + (size_t)b * A_CNT * NC_CNT;
    const float4* pbb = (const float4*)(pb + (size_t)b * A_CNT * 4);

    for (int a = threadIdx.x; a < A_CNT; a += 256) {
        float ax = ap[2 * a], ay = ap[2 * a + 1];
        float dmin = fminf(fminf(ax - g.x, ay - g.y), fminf(g.z - ax, g.w - ay));
        bool v = mg && (dmin > EPS_IN);
        float al = 0.f;
        if (v) {
            float4 p = pbb[a];
            float ix = fminf(g.z, p.z) - fmaxf(g.x, p.x);
            float iy = fminf(g.w, p.w) - fmaxf(g.y, p.y);
            float inter = fmaxf(ix, 0.f) * fmaxf(iy, 0.f);
            float area_p = (p.z - p.x) * (p.w - p.y);
            float ov = inter / (area_g + area_p - inter + 1e-7f);
            ov = fmaxf(ov, 0.f);
            float sc = psb[(size_t)a * NC_CNT + lbl];
            float o2 = ov * ov;
            al = sc * (o2 * o2 * o2);
        }
        vals[a] = al;
        validb[a] = v ? 1 : 0;
    }
    __syncthreads();

    for (int k = 0; k < TOPK; k++) {
        float best = -1.f; int bi = 0x7fffffff;
        for (int a = threadIdx.x; a < A_CNT; a += 256) {
            float v = vals[a];
            if (v > best) { best = v; bi = a; }      // ascending: first max kept
        }
        rv[threadIdx.x] = best; ri[threadIdx.x] = bi;
        __syncthreads();
        for (int s = 128; s > 0; s >>= 1) {
            if (threadIdx.x < s) {
                float v2 = rv[threadIdx.x + s]; int i2 = ri[threadIdx.x + s];
                if (v2 > rv[threadIdx.x] || (v2 == rv[threadIdx.x] && i2 < ri[threadIdx.x])) {
                    rv[threadIdx.x] = v2; ri[threadIdx.x] = i2;
                }
            }
            __syncthreads();
        }
        if (threadIdx.x == 0) { sel[k] = ri[0]; selAl[k] = rv[0]; vals[ri[0]] = -1.f; }
        __syncthreads();
    }

    // epilogue: 13 threads emit compact entries + posmask bits
    if (threadIdx.x < TOPK) {
        int k = threadIdx.x;
        int i = sel[k];
        bool v = validb[i] != 0;
        float al = v ? selAl[k] : 0.f;
        float ov = 0.f;
        if (v) {
            float4 p = pbb[i];
            float ix = fminf(g.z, p.z) - fmaxf(g.x, p.x);
            float iy = fminf(g.w, p.w) - fmaxf(g.y, p.y);
            float inter = fmaxf(ix, 0.f) * fmaxf(iy, 0.f);
            float area_p = (p.z - p.x) * (p.w - p.y);
            ov = inter / (area_g + area_p - inter + 1e-7f);
            ov = fmaxf(ov, 0.f);
            atomicOr(&posmask[(size_t)b * A_CNT + i], 1u << n);
        }
        cIdx[bn * TOPK + k] = i;
        cAl [bn * TOPK + k] = al;
        cOv [bn * TOPK + k] = ov;
    }
}

// ---------- K2: per (b,a): fg, conflict resolve (recompute column), row-max scatter ----------
__global__ void __launch_bounds__(256) k2(const float* __restrict__ ps, const float* __restrict__ pb,
        const float* __restrict__ ap, const int* __restrict__ gl,
        const float* __restrict__ gb, const float* __restrict__ mgt,
        const unsigned int* __restrict__ posmask,
        const int* __restrict__ cIdx, const float* __restrict__ cAl, const float* __restrict__ cOv,
        int* __restrict__ tgi, float* __restrict__ alT, float* __restrict__ fgw,
        int* __restrict__ posAl, int* __restrict__ posOv) {
    __shared__ float4 gs[N_CNT];
    __shared__ float  mgs[N_CNT];
    __shared__ int    lbls[N_CNT];
    __shared__ int    sIdx[N_CNT][TOPK];
    __shared__ float  sAl[N_CNT][TOPK];
    __shared__ float  sOv[N_CNT][TOPK];
    int b = blockIdx.y;
    if (threadIdx.x < N_CNT) {
        int bn = b * N_CNT + threadIdx.x;
        gs[threadIdx.x]   = ((const float4*)gb)[bn];
        mgs[threadIdx.x]  = mgt[bn];
        lbls[threadIdx.x] = min(max(gl[bn], 0), NC_CNT - 1);
    }
    for (int t = threadIdx.x; t < N_CNT * TOPK; t += 256) {
        int r = t / TOPK, k = t - r * TOPK;
        int src = b * N_CNT * TOPK + t;
        sIdx[r][k] = cIdx[src];
        sAl [r][k] = cAl [src];
        sOv [r][k] = cOv [src];
    }
    __syncthreads();
    int a = blockIdx.x * 256 + threadIdx.x;
    if (a >= A_CNT) return;
    size_t ba = (size_t)b * A_CNT + a;
    unsigned int pm = posmask[ba];
    int fg = __popc(pm);
    int t = 0; float al = 0.f; float fgv = 0.f;
    if (fg == 1) {
        t = __ffs(pm) - 1;
        float ov = 0.f;
#pragma unroll
        for (int k = 0; k < TOPK; k++)
            if (sIdx[t][k] == a) { al = sAl[t][k]; ov = sOv[t][k]; }
        atomicMax(&posAl[b * N_CNT + t], __float_as_int(al));
        atomicMax(&posOv[b * N_CNT + t], __float_as_int(ov));
        fgv = 1.f;
    } else if (fg > 1) {
        float ax = ap[2 * a], ay = ap[2 * a + 1];
        float4 p = ((const float4*)pb)[ba];
        float area_p = (p.z - p.x) * (p.w - p.y);
        float bo = -1.f; int bt = 0;
        for (int nn = 0; nn < N_CNT; nn++) {
            float4 g = gs[nn];
            float dmin = fminf(fminf(ax - g.x, ay - g.y), fminf(g.z - ax, g.w - ay));
            bool v = (mgs[nn] > 0.f) && (dmin > EPS_IN);
            float ov = 0.f;
            if (v) {
                float ix = fminf(g.z, p.z) - fmaxf(g.x, p.x);
                float iy = fminf(g.w, p.w) - fmaxf(g.y, p.y);
                float inter = fmaxf(ix, 0.f) * fmaxf(iy, 0.f);
                float area_g = (g.z - g.x) * (g.w - g.y);
                ov = inter / (area_g + area_p - inter + 1e-7f);
                ov = fmaxf(ov, 0.f);
            }
            if (ov > bo) { bo = ov; bt = nn; }       // first max (numpy argmax)
        }
        t = bt;
        float sc = ps[ba * NC_CNT + lbls[t]];
        float o2 = bo * bo;
        al = sc * (o2 * o2 * o2);
        atomicMax(&posAl[b * N_CNT + t], __float_as_int(al));
        atomicMax(&posOv[b * N_CNT + t], __float_as_int(bo));
        fgv = 1.f;
    }
    tgi[ba] = t;
    alT[ba] = al;
    fgw[ba] = fgv;
}

// ---------- K3: fused norm + one-hot scores (float4) + bbox gather + fg ----------
__global__ void __launch_bounds__(256) k3(const int* __restrict__ tgi, const float* __restrict__ alT,
        const float* __restrict__ fgw, const int* __restrict__ posAl, const int* __restrict__ posOv,
        const int* __restrict__ gl, const float* __restrict__ gb,
        float* __restrict__ out_bbox, float* __restrict__ out_scores, float* __restrict__ out_fg) {
    int idx = blockIdx.x * 256 + threadIdx.x;   // over BA*20 float4s
    if (idx >= B_CNT * A_CNT * (NC_CNT / 4)) return;
    int ba = idx / 20;
    int q  = idx - ba * 20;
    int b  = ba / A_CNT;
    int t  = tgi[ba];
    int bn = b * N_CNT + t;
    float fgv = fgw[ba];
    float norm = 0.f;
    if (fgv > 0.f) {
        float pa = __int_as_float(posAl[bn]);
        float po = __int_as_float(posOv[bn]);
        norm = alT[ba] * po / (pa + 1e-9f);
    }
    int lbl = min(max(gl[bn], 0), NC_CNT - 1);
    int c0 = q * 4;
    float4 v;
    v.x = (fgv > 0.f && lbl == c0    ) ? norm : 0.f;
    v.y = (fgv > 0.f && lbl == c0 + 1) ? norm : 0.f;
    v.z = (fgv > 0.f && lbl == c0 + 2) ? norm : 0.f;
    v.w = (fgv > 0.f && lbl == c0 + 3) ? norm : 0.f;
    ((float4*)out_scores)[idx] = v;
    if (q == 0) {
        ((float4*)out_bbox)[ba] = ((const float4*)gb)[bn];
        out_fg[ba] = fgv;
    }
}

extern "C" void kernel_launch(void* const* d_in, const int* in_sizes, int n_in,
                              void* d_out, int out_size, void* d_ws, size_t ws_size,
                              hipStream_t stream) {
    const float* pred_scores   = (const float*)d_in[0];   // (32, 8400, 80)
    const float* pred_bboxes   = (const float*)d_in[1];   // (32, 8400, 4)
    const float* anchor_points = (const float*)d_in[2];   // (8400, 2)
    const int*   gt_labels     = (const int*)d_in[3];     // (32, 32, 1)
    const float* gt_bboxes     = (const float*)d_in[4];   // (32, 32, 4)
    const float* mask_gt       = (const float*)d_in[5];   // (32, 32, 1)

    const int BA  = B_CNT * A_CNT;           // 268,800
    const int BN  = B_CNT * N_CNT;           // 1024

    // workspace layout (posmask + posAl + posOv contiguous for one memset)
    char* w = (char*)d_ws;
    unsigned int* posmask = (unsigned int*)w;  w += (size_t)BA * 4;
    int*   posAl   = (int*)w;                  w += (size_t)BN * 4;
    int*   posOv   = (int*)w;                  w += (size_t)BN * 4;
    int*   cIdx    = (int*)w;                  w += (size_t)BN * TOPK * 4;
    float* cAl     = (float*)w;                w += (size_t)BN * TOPK * 4;
    float* cOv     = (float*)w;                w += (size_t)BN * TOPK * 4;
    int*   tgi     = (int*)w;                  w += (size_t)BA * 4;
    float* alT     = (float*)w;                w += (size_t)BA * 4;
    float* fgw     = (float*)w;                w += (size_t)BA * 4;

    // output layout: bboxes (BA*4) | scores (BA*80) | fg (BA)
    float* out_bbox   = (float*)d_out;
    float* out_scores = out_bbox + (size_t)BA * 4;
    float* out_fg     = out_scores + (size_t)BA * NC_CNT;

    hipMemsetAsync(posmask, 0, (size_t)(BA + 2 * BN) * 4, stream);

    dim3 blk(256);
    k1<<<dim3(BN), blk, 0, stream>>>(pred_scores, pred_bboxes, anchor_points,
                                     gt_labels, gt_bboxes, mask_gt,
                                     posmask, cIdx, cAl, cOv);
    k2<<<dim3((A_CNT + 255) / 256, B_CNT), blk, 0, stream>>>(pred_scores, pred_bboxes,
                                     anchor_points, gt_labels, gt_bboxes, mask_gt,
                                     posmask, cIdx, cAl, cOv,
                                     tgi, alT, fgw, posAl, posOv);
    k3<<<dim3((BA * (NC_CNT / 4) + 255) / 256), blk, 0, stream>>>(tgi, alT, fgw,
                                     posAl, posOv, gt_labels, gt_bboxes,
                                     out_bbox, out_scores, out_fg);
}

// Round 4
// 212.080 us; speedup vs baseline: 1.2781x; 1.2689x over previous
//
#include <hip/hip_runtime.h>

#define B_CNT 32
#define N_CNT 32
#define A_CNT 8400
#define NC_CNT 80
#define TOPK 13
#define EPS_IN 1e-9f

typedef unsigned long long u64;
typedef unsigned int u32;

// key packing: (float_bits(al) << 32) | (0xFFFFFFFF - idx)
// al >= 0 so uint order == float order; larger key == larger val, or equal val & smaller idx.
// Matches jax.lax.top_k stable ordering exactly. Sentinel 0 < any real key.

// ---------- K1: per (b,n) row: inline align, reg top-13 + shuffle merge, compact lists ----------
__global__ void __launch_bounds__(256) k1(const float* __restrict__ ps, const float* __restrict__ pb,
        const float* __restrict__ ap, const int* __restrict__ gl,
        const float* __restrict__ gb, const float* __restrict__ mgt,
        int* __restrict__ cIdx, float* __restrict__ cAl, float* __restrict__ cOv) {
    __shared__ u64 wmax[TOPK][4];
    __shared__ u64 winsh[TOPK];
    int bn = blockIdx.x;            // b*32+n
    int b = bn >> 5;
    float4 g = ((const float4*)gb)[bn];
    bool mg = mgt[bn] > 0.f;
    int lbl = min(max(gl[bn], 0), NC_CNT - 1);
    float area_g = (g.z - g.x) * (g.w - g.y);
    const float*  psb = ps + (size_t)b * A_CNT * NC_CNT;
    const float4* pbb = (const float4*)(pb + (size_t)b * A_CNT * 4);
    const float2* ap2 = (const float2*)ap;
    int tid = threadIdx.x;

    // phase 1: per-thread sorted top-13 in registers (static indices only)
    u64 keys[TOPK];
#pragma unroll
    for (int j = 0; j < TOPK; j++) keys[j] = 0;

    for (int a = tid; a < A_CNT; a += 256) {
        float2 aq = ap2[a];
        float dmin = fminf(fminf(aq.x - g.x, aq.y - g.y), fminf(g.z - aq.x, g.w - aq.y));
        bool v = mg && (dmin > EPS_IN);
        float al = 0.f;
        if (v) {
            float4 p = pbb[a];
            float ix = fminf(g.z, p.z) - fmaxf(g.x, p.x);
            float iy = fminf(g.w, p.w) - fmaxf(g.y, p.y);
            float inter = fmaxf(ix, 0.f) * fmaxf(iy, 0.f);
            float area_p = (p.z - p.x) * (p.w - p.y);
            float ov = inter / (area_g + area_p - inter + 1e-7f);
            ov = fmaxf(ov, 0.f);
            float sc = psb[(size_t)a * NC_CNT + lbl];
            float o2 = ov * ov;
            al = sc * (o2 * o2 * o2);
        }
        u64 kc = ((u64)__float_as_uint(al) << 32) | (u64)(0xFFFFFFFFu - (u32)a);
        if (kc > keys[TOPK - 1]) {
            keys[TOPK - 1] = kc;
#pragma unroll
            for (int j = TOPK - 1; j > 0; --j) {
                if (keys[j] > keys[j - 1]) { u64 t2 = keys[j]; keys[j] = keys[j - 1]; keys[j - 1] = t2; }
            }
        }
    }

    // phase 2: 13 passes, each: wave butterfly on keys[0], 1 barrier, redundant cross-wave max
    int wid = tid >> 6;
    for (int pass = 0; pass < TOPK; ++pass) {
        u64 m = keys[0];                       // sorted: slot 0 is thread max
#pragma unroll
        for (int off = 1; off <= 32; off <<= 1) {
            u64 o = __shfl_xor(m, off);
            if (o > m) m = o;
        }
        if ((tid & 63) == 0) wmax[pass][wid] = m;
        __syncthreads();
        u64 w = wmax[pass][0];
#pragma unroll
        for (int q = 1; q < 4; q++) { u64 o = wmax[pass][q]; if (o > w) w = o; }
        if (tid == 0) winsh[pass] = w;
        // remove winner from owner's sorted list (static-index compaction)
        bool f = false;
#pragma unroll
        for (int j = 0; j < TOPK - 1; ++j) {
            f = f || (keys[j] == w);
            keys[j] = f ? keys[j + 1] : keys[j];
        }
        f = f || (keys[TOPK - 1] == w);
        if (f) keys[TOPK - 1] = 0;
    }
    __syncthreads();

    // epilogue: decode 13 winners, recompute validity + iou, emit compact lists
    if (tid < TOPK) {
        u64 w = winsh[tid];
        int i = (int)(0xFFFFFFFFu - (u32)(w & 0xFFFFFFFFull));
        float al = __uint_as_float((u32)(w >> 32));
        float2 aq = ap2[i];
        float dmin = fminf(fminf(aq.x - g.x, aq.y - g.y), fminf(g.z - aq.x, g.w - aq.y));
        bool v = mg && (dmin > EPS_IN);
        int ci = -1; float ov = 0.f;
        if (v) {
            float4 p = pbb[i];
            float ix = fminf(g.z, p.z) - fmaxf(g.x, p.x);
            float iy = fminf(g.w, p.w) - fmaxf(g.y, p.y);
            float inter = fmaxf(ix, 0.f) * fmaxf(iy, 0.f);
            float area_p = (p.z - p.x) * (p.w - p.y);
            ov = inter / (area_g + area_p - inter + 1e-7f);
            ov = fmaxf(ov, 0.f);
            ci = i;
        }
        cIdx[bn * TOPK + tid] = ci;
        cAl [bn * TOPK + tid] = v ? al : 0.f;
        cOv [bn * TOPK + tid] = ov;
    }
}

// ---------- K2: per (b,a): membership over compact lists, conflict resolve, row-max scatter ----------
__global__ void __launch_bounds__(256) k2(const float* __restrict__ ps, const float* __restrict__ pb,
        const float* __restrict__ ap, const int* __restrict__ gl,
        const float* __restrict__ gb, const float* __restrict__ mgt,
        const int* __restrict__ cIdx, const float* __restrict__ cAl, const float* __restrict__ cOv,
        int* __restrict__ tgi, float* __restrict__ alT, float* __restrict__ fgw,
        int* __restrict__ posAl, int* __restrict__ posOv) {
    __shared__ int   sIdx[N_CNT][TOPK];
    __shared__ float sAl[N_CNT][TOPK];
    __shared__ float sOv[N_CNT][TOPK];
    __shared__ float4 gs[N_CNT];
    __shared__ float  mgs[N_CNT];
    __shared__ int    lbls[N_CNT];
    int b = blockIdx.y;
    if (threadIdx.x < N_CNT) {
        int bn = b * N_CNT + threadIdx.x;
        gs[threadIdx.x]   = ((const float4*)gb)[bn];
        mgs[threadIdx.x]  = mgt[bn];
        lbls[threadIdx.x] = min(max(gl[bn], 0), NC_CNT - 1);
    }
    for (int t = threadIdx.x; t < N_CNT * TOPK; t += 256) {
        int r = t / TOPK, k = t - r * TOPK;
        int src = b * N_CNT * TOPK + t;
        sIdx[r][k] = cIdx[src];
        sAl [r][k] = cAl [src];
        sOv [r][k] = cOv [src];
    }
    __syncthreads();
    int a = blockIdx.x * 256 + threadIdx.x;
    if (a >= A_CNT) return;
    size_t ba = (size_t)b * A_CNT + a;

    int fg = 0, t = 0, mk = -1;
    for (int nn = 0; nn < N_CNT; nn++) {
        int m = -1;
#pragma unroll
        for (int k = 0; k < TOPK; k++)
            if (sIdx[nn][k] == a) m = k;       // broadcast LDS reads: conflict-free
        if (m >= 0) { if (fg == 0) { t = nn; mk = m; } fg++; }
    }

    float al = 0.f, fgv = 0.f;
    if (fg == 1) {
        al = sAl[t][mk];
        float ov = sOv[t][mk];
        atomicMax(&posAl[b * N_CNT + t], __float_as_int(al));
        atomicMax(&posOv[b * N_CNT + t], __float_as_int(ov));
        fgv = 1.f;
    } else if (fg > 1) {
        float ax = ap[2 * a], ay = ap[2 * a + 1];
        float4 p = ((const float4*)pb)[ba];
        float area_p = (p.z - p.x) * (p.w - p.y);
        float bo = -1.f; int bt = 0;
        for (int nn = 0; nn < N_CNT; nn++) {
            float4 g = gs[nn];
            float dmin = fminf(fminf(ax - g.x, ay - g.y), fminf(g.z - ax, g.w - ay));
            bool v = (mgs[nn] > 0.f) && (dmin > EPS_IN);
            float ov = 0.f;
            if (v) {
                float ix = fminf(g.z, p.z) - fmaxf(g.x, p.x);
                float iy = fminf(g.w, p.w) - fmaxf(g.y, p.y);
                float inter = fmaxf(ix, 0.f) * fmaxf(iy, 0.f);
                float area_g = (g.z - g.x) * (g.w - g.y);
                ov = inter / (area_g + area_p - inter + 1e-7f);
                ov = fmaxf(ov, 0.f);
            }
            if (ov > bo) { bo = ov; bt = nn; }   // first max (numpy argmax)
        }
        t = bt;
        float sc = ps[ba * NC_CNT + lbls[t]];
        float o2 = bo * bo;
        al = sc * (o2 * o2 * o2);
        atomicMax(&posAl[b * N_CNT + t], __float_as_int(al));
        atomicMax(&posOv[b * N_CNT + t], __float_as_int(bo));
        fgv = 1.f;
    }
    tgi[ba] = t;
    alT[ba] = al;
    fgw[ba] = fgv;
}

// ---------- K3: fused norm + one-hot scores (float4) + bbox gather + fg ----------
__global__ void __launch_bounds__(256) k3(const int* __restrict__ tgi, const float* __restrict__ alT,
        const float* __restrict__ fgw, const int* __restrict__ posAl, const int* __restrict__ posOv,
        const int* __restrict__ gl, const float* __restrict__ gb,
        float* __restrict__ out_bbox, float* __restrict__ out_scores, float* __restrict__ out_fg) {
    int idx = blockIdx.x * 256 + threadIdx.x;   // over BA*20 float4s
    if (idx >= B_CNT * A_CNT * (NC_CNT / 4)) return;
    int ba = idx / 20;
    int q  = idx - ba * 20;
    int b  = ba / A_CNT;
    int t  = tgi[ba];
    int bn = b * N_CNT + t;
    float fgv = fgw[ba];
    float norm = 0.f;
    if (fgv > 0.f) {
        float pa = __int_as_float(posAl[bn]);
        float po = __int_as_float(posOv[bn]);
        norm = alT[ba] * po / (pa + 1e-9f);
    }
    int lbl = min(max(gl[bn], 0), NC_CNT - 1);
    int c0 = q * 4;
    float4 v;
    v.x = (fgv > 0.f && lbl == c0    ) ? norm : 0.f;
    v.y = (fgv > 0.f && lbl == c0 + 1) ? norm : 0.f;
    v.z = (fgv > 0.f && lbl == c0 + 2) ? norm : 0.f;
    v.w = (fgv > 0.f && lbl == c0 + 3) ? norm : 0.f;
    ((float4*)out_scores)[idx] = v;
    if (q == 0) {
        ((float4*)out_bbox)[ba] = ((const float4*)gb)[bn];
        out_fg[ba] = fgv;
    }
}

extern "C" void kernel_launch(void* const* d_in, const int* in_sizes, int n_in,
                              void* d_out, int out_size, void* d_ws, size_t ws_size,
                              hipStream_t stream) {
    const float* pred_scores   = (const float*)d_in[0];   // (32, 8400, 80)
    const float* pred_bboxes   = (const float*)d_in[1];   // (32, 8400, 4)
    const float* anchor_points = (const float*)d_in[2];   // (8400, 2)
    const int*   gt_labels     = (const int*)d_in[3];     // (32, 32, 1)
    const float* gt_bboxes     = (const float*)d_in[4];   // (32, 32, 4)
    const float* mask_gt       = (const float*)d_in[5];   // (32, 32, 1)

    const int BA = B_CNT * A_CNT;            // 268,800
    const int BN = B_CNT * N_CNT;            // 1024

    // workspace layout (posAl/posOv first: one tiny memset)
    char* w = (char*)d_ws;
    int*   posAl   = (int*)w;                  w += (size_t)BN * 4;
    int*   posOv   = (int*)w;                  w += (size_t)BN * 4;
    int*   cIdx    = (int*)w;                  w += (size_t)BN * TOPK * 4;
    float* cAl     = (float*)w;                w += (size_t)BN * TOPK * 4;
    float* cOv     = (float*)w;                w += (size_t)BN * TOPK * 4;
    int*   tgi     = (int*)w;                  w += (size_t)BA * 4;
    float* alT     = (float*)w;                w += (size_t)BA * 4;
    float* fgw     = (float*)w;                w += (size_t)BA * 4;

    // output layout: bboxes (BA*4) | scores (BA*80) | fg (BA)
    float* out_bbox   = (float*)d_out;
    float* out_scores = out_bbox + (size_t)BA * 4;
    float* out_fg     = out_scores + (size_t)BA * NC_CNT;

    hipMemsetAsync(posAl, 0, (size_t)2 * BN * 4, stream);

    dim3 blk(256);
    k1<<<dim3(BN), blk, 0, stream>>>(pred_scores, pred_bboxes, anchor_points,
                                     gt_labels, gt_bboxes, mask_gt,
                                     cIdx, cAl, cOv);
    k2<<<dim3((A_CNT + 255) / 256, B_CNT), blk, 0, stream>>>(pred_scores, pred_bboxes,
                                     anchor_points, gt_labels, gt_bboxes, mask_gt,
                                     cIdx, cAl, cOv,
                                     tgi, alT, fgw, posAl, posOv);
    k3<<<dim3((BA * (NC_CNT / 4) + 255) / 256), blk, 0, stream>>>(tgi, alT, fgw,
                                     posAl, posOv, gt_labels, gt_bboxes,
                                     out_bbox, out_scores, out_fg);
}